// Round 2
// baseline (294.630 us; speedup 1.0000x reference)
//
#include <hip/hip_runtime.h>
#include <cstdint>
#include <cstddef>

// Qwen3AttentionModified: B=1 S=2048 D=2048 H=16 KVH=8 HD=128
// cast hs->bf16; transpose+cast weights; QKV GEMM; RoPE -> Q [h][s][d] bf16 +
// K pre-swizzled 32KB tiles; V -> pre-swizzled [d][key] tiles; chunked split-K
// attention (<=4 key-tiles/block, fp32 partials); reduce -> AO bf16; O GEMM.

namespace {
constexpr int kS = 2048;
constexpr int kD = 2048;
constexpr int kH = 16;
constexpr int kKVH = 8;
constexpr int kHD = 128;
constexpr float kScale = 0.08838834764831845f;  // 128^-0.5
constexpr size_t MB = 1u << 20;
}  // namespace

using f32x4 = __attribute__((ext_vector_type(4))) float;
using bfrag = __attribute__((ext_vector_type(8))) short;   // 8 x bf16 (4 VGPR)
using float4v = __attribute__((ext_vector_type(4))) float;
using short4v = __attribute__((ext_vector_type(4))) short;

__device__ __forceinline__ unsigned short f2b(float f) {
  union { float f; unsigned u; } x; x.f = f;
  unsigned r = x.u + 0x7FFFu + ((x.u >> 16) & 1u);  // RNE
  return (unsigned short)(r >> 16);
}

__device__ __forceinline__ void gload_lds16(const void* g, void* l) {
  __builtin_amdgcn_global_load_lds(
      (const __attribute__((address_space(1))) unsigned*)g,
      (__attribute__((address_space(3))) unsigned*)l, 16, 0, 0);
}

// ---------------- cast fp32 -> bf16 (contiguous, vectorized) ----------------
__global__ __launch_bounds__(256) void qwen_cast_bf16(const float* __restrict__ in,
                                                      unsigned short* __restrict__ out,
                                                      int n4) {
  int i = blockIdx.x * 256 + threadIdx.x;
  if (i >= n4) return;
  float4v v = *(const float4v*)(in + (size_t)i * 4);
  short4v o;
  o[0] = (short)f2b(v[0]); o[1] = (short)f2b(v[1]);
  o[2] = (short)f2b(v[2]); o[3] = (short)f2b(v[3]);
  *(short4v*)(out + (size_t)i * 4) = o;
}

// ------------- transpose + cast: in fp32 [R][C] -> out bf16 [C][ldo] -------------
__global__ __launch_bounds__(256) void qwen_tw(const float* __restrict__ in, int R, int C,
                                               unsigned short* __restrict__ out, int ldo) {
  __shared__ float t[64][65];
  int c0 = blockIdx.x * 64, r0 = blockIdx.y * 64;
  int tr = threadIdx.x >> 6, tc = threadIdx.x & 63;
#pragma unroll
  for (int p = 0; p < 16; ++p) {
    int i = p * 4 + tr;
    t[i][tc] = in[(size_t)(r0 + i) * C + c0 + tc];
  }
  __syncthreads();
#pragma unroll
  for (int p = 0; p < 16; ++p) {
    int i = p * 4 + tr;
    out[(size_t)(c0 + i) * ldo + r0 + tc] = f2b(t[tc][i]);
  }
}

// ------------- GEMM: C[M][N] fp32 = A[M][K] bf16 @ Bt[N][K] bf16 (m97 structure) -------------
__global__ __launch_bounds__(256) void qwen_gemm_bt(const unsigned short* __restrict__ A,
                                                    const unsigned short* __restrict__ Bt,
                                                    float* __restrict__ C,
                                                    int M, int N, int K) {
  __shared__ unsigned short As[128 * 32];
  __shared__ unsigned short Bs[128 * 32];
  const int tid = threadIdx.x;
  const int lane = tid & 63;
  const int w = tid >> 6;
  const int wr = w >> 1, wc = w & 1;
  const int row0 = blockIdx.x * 128, col0 = blockIdx.y * 128;
  f32x4 acc[4][4] = {};
  const int koff = (lane >> 4) << 3;
  const int rA = wr * 64 + (lane & 15);
  const int rB = wc * 64 + (lane & 15);
  for (int kt = 0; kt < K; kt += 32) {
#pragma unroll
    for (int c = 0; c < 2; ++c) {
      int off = w * 2048 + c * 1024;
      int e = (off >> 1) + lane * 8;
      int r = e >> 5, cc = e & 31;
      gload_lds16(A + (size_t)(row0 + r) * K + kt + cc, (char*)As + off);
      gload_lds16(Bt + (size_t)(col0 + r) * K + kt + cc, (char*)Bs + off);
    }
    __syncthreads();
    bfrag aF[4], bF[4];
#pragma unroll
    for (int m = 0; m < 4; ++m) aF[m] = *(const bfrag*)(As + (rA + m * 16) * 32 + koff);
#pragma unroll
    for (int n = 0; n < 4; ++n) bF[n] = *(const bfrag*)(Bs + (rB + n * 16) * 32 + koff);
#pragma unroll
    for (int m = 0; m < 4; ++m)
#pragma unroll
      for (int n = 0; n < 4; ++n)
        acc[m][n] = __builtin_amdgcn_mfma_f32_16x16x32_bf16(aF[m], bF[n], acc[m][n], 0, 0, 0);
    __syncthreads();
  }
  const int cr = (lane >> 4) << 2;
  const int cc2 = lane & 15;
#pragma unroll
  for (int m = 0; m < 4; ++m)
#pragma unroll
    for (int n = 0; n < 4; ++n) {
      int r = row0 + wr * 64 + m * 16 + cr;
      int c = col0 + wc * 64 + n * 16 + cc2;
#pragma unroll
      for (int j = 0; j < 4; ++j) C[(size_t)(r + j) * N + c] = acc[m][n][j];
    }
}

// ------------- RoPE epilogue; Q -> [h][s][d] bf16; K -> pre-swizzled 32KB tiles -------------
// K tile image (per kvh, kt): row key in [0,128), byte = key*256 + ((d*2) ^ ((key&7)<<4))
__global__ __launch_bounds__(256) void qwen_rope_qk(const float* __restrict__ Cqkv,
                                                    const float* __restrict__ cosb,
                                                    const float* __restrict__ sinb,
                                                    const float* __restrict__ qnw,
                                                    const float* __restrict__ knw,
                                                    const float* __restrict__ qden,
                                                    const float* __restrict__ kden,
                                                    unsigned short* __restrict__ Qb,
                                                    unsigned short* __restrict__ Kswz) {
  int s = blockIdx.x;
  int t = threadIdx.x;
  const float* row = Cqkv + (size_t)s * 4096;
  const float* cs = cosb + (size_t)s * kHD;
  const float* sn = sinb + (size_t)s * kHD;
#pragma unroll
  for (int rep = 0; rep < 8; ++rep) {  // 2048 Q elems
    int idx = rep * 256 + t;
    int h = idx >> 7, d = idx & 127;
    float dn = qden[s * kH + h];
    float v = row[idx] * dn * qnw[d];
    float pv = row[(h << 7) + (d ^ 64)] * dn * qnw[d ^ 64];
    float rot = (d < 64) ? -pv : pv;
    Qb[((size_t)h * kS + s) * kHD + d] = f2b(v * cs[d] + rot * sn[d]);
  }
  const int kt = s >> 7, key = s & 127;
#pragma unroll
  for (int rep = 0; rep < 4; ++rep) {  // 1024 K elems
    int idx = rep * 256 + t;
    int h = idx >> 7, d = idx & 127;
    float dn = kden[s * kKVH + h];
    float v = row[2048 + idx] * dn * knw[d];
    float pv = row[2048 + (h << 7) + (d ^ 64)] * dn * knw[d ^ 64];
    float rot = (d < 64) ? -pv : pv;
    size_t base = (((size_t)h * 16 + kt) * 128 + key) * 256;
    *(unsigned short*)((char*)Kswz + base + ((d * 2) ^ ((key & 7) << 4))) =
        f2b(v * cs[d] + rot * sn[d]);
  }
}

// ------------- V -> pre-swizzled tiles: row dd in [0,128), byte = dd*256 + ((key*2)^((dd&7)<<4)) -------------
__global__ __launch_bounds__(256) void qwen_vtr(const float* __restrict__ Cqkv,
                                                unsigned short* __restrict__ Vswz) {
  __shared__ float t[64][65];
  int kvh = blockIdx.x, st = blockIdx.y, dt = blockIdx.z;
  int s0 = st * 64, d0 = dt * 64;
  int tr = threadIdx.x >> 6, tc = threadIdx.x & 63;
#pragma unroll
  for (int p = 0; p < 16; ++p) {
    int i = p * 4 + tr;
    t[i][tc] = Cqkv[(size_t)(s0 + i) * 4096 + 3072 + (kvh << 7) + d0 + tc];
  }
  __syncthreads();
  const int kt = st >> 1;
  const int key = (st & 1) * 64 + tc;
#pragma unroll
  for (int p = 0; p < 16; ++p) {
    int i = p * 4 + tr;
    int dd = d0 + i;
    size_t base = (((size_t)kvh * 16 + kt) * 128 + dd) * 256;
    *(unsigned short*)((char*)Vswz + base + ((key * 2) ^ ((dd & 7) << 4))) = f2b(t[tc][i]);
  }
}

// ------------- attention: chunked split-K, one block per (h, qt, <=4 key-tiles) -------------
__global__ __launch_bounds__(256, 2) void qwen_attn(const unsigned short* __restrict__ Qb,
                                                    const unsigned short* __restrict__ Kswz,
                                                    const unsigned short* __restrict__ Vswz,
                                                    const float* __restrict__ rd,
                                                    float* __restrict__ Pacc) {
  __shared__ unsigned short KVs[128 * 128];  // K/V time-share (32KB)
  __shared__ unsigned short Ps[128 * 128];   // P bf16, swizzled (32KB)
  const int bx = blockIdx.x;
  const int h = bx / 40;
  int r = bx - h * 40;
  int qt = 0, c0 = 0;
  while (r >= c0 + (qt >> 2) + 1) { c0 += (qt >> 2) + 1; ++qt; }
  const int chunk = r - c0;
  const int kt0 = chunk * 4;
  const int ktend = min(kt0 + 4, qt + 1);
  const int kvh = h >> 1;
  const int tid = threadIdx.x, lane = tid & 63, w = tid >> 6;
  const int wr = w >> 1, wc = w & 1;
  const int koff = (lane >> 4) << 3;
  const int l15 = lane & 15;

  // Q fragments in registers
  bfrag qF[4][4];
  {
    const unsigned short* Qg = Qb + ((size_t)h * kS + qt * 128) * kHD;
#pragma unroll
    for (int m = 0; m < 4; ++m)
#pragma unroll
      for (int kc = 0; kc < 4; ++kc)
        qF[m][kc] = *(const bfrag*)(Qg + (size_t)(wr * 64 + m * 16 + l15) * kHD + kc * 32 + koff);
  }
  float ascl[4][4], bshift[4][4];
  {
    const float* rdp = rd + (size_t)h * kS + qt * 128 + wr * 64 + ((lane >> 4) << 2);
#pragma unroll
    for (int m = 0; m < 4; ++m)
#pragma unroll
      for (int j = 0; j < 4; ++j) {
        float inv = 1.0f / rdp[m * 16 + j];
        ascl[m][j] = kScale * inv;
        bshift[m][j] = 7.0f * inv;
      }
  }
  f32x4 outa[4][4] = {};

  for (int kt = kt0; kt < ktend; ++kt) {
    // stage K tile: pre-swizzled global image -> linear LDS copy (global_load_lds x16B)
    const char* Kt = (const char*)Kswz + (((size_t)kvh * 16 + kt) << 15);
#pragma unroll
    for (int it = 0; it < 8; ++it) {
      int off = w * 8192 + it * 1024;
      gload_lds16(Kt + off + lane * 16, (char*)KVs + off);
    }
    __syncthreads();
    // QK^T
    f32x4 sc[4][4] = {};
#pragma unroll
    for (int n = 0; n < 4; ++n) {
      int key = wc * 64 + n * 16 + l15;
      bfrag kF[4];
#pragma unroll
      for (int kc = 0; kc < 4; ++kc) {
        int kb = kc * 32 + koff;
        kF[kc] = *(const bfrag*)((char*)KVs + key * 256 + ((kb * 2) ^ ((key & 7) << 4)));
      }
#pragma unroll
      for (int m = 0; m < 4; ++m)
#pragma unroll
        for (int kc = 0; kc < 4; ++kc)
          sc[m][n] = __builtin_amdgcn_mfma_f32_16x16x32_bf16(qF[m][kc], kF[kc], sc[m][n], 0, 0, 0);
    }
    // elementwise ((s*scale + mask + 7)/rd)^8 -> Ps bf16 (swizzled)
    const bool diag = (kt == qt);
#pragma unroll
    for (int m = 0; m < 4; ++m)
#pragma unroll
      for (int j = 0; j < 4; ++j) {
        int rloc = wr * 64 + m * 16 + ((lane >> 4) << 2) + j;
        float a = ascl[m][j], b = bshift[m][j];
#pragma unroll
        for (int n = 0; n < 4; ++n) {
          int c = wc * 64 + n * 16 + l15;
          bool ok = !diag || (c <= rloc);  // masked: (-7+7)=0 shift -> exact
          float y = sc[m][n][j] * a + (ok ? b : 0.0f);
          float y2 = y * y, y4 = y2 * y2;
          int ba = rloc * 256 + ((c * 2) ^ ((rloc & 7) << 4));
          *(unsigned short*)((char*)Ps + ba) = f2b(y4 * y4);
        }
      }
    __syncthreads();  // K reads done + Ps visible
    // stage V tile into same buffer
    const char* Vt = (const char*)Vswz + (((size_t)kvh * 16 + kt) << 15);
#pragma unroll
    for (int it = 0; it < 8; ++it) {
      int off = w * 8192 + it * 1024;
      gload_lds16(Vt + off + lane * 16, (char*)KVs + off);
    }
    __syncthreads();
    // PV: out[q][hd] += P[q][key] @ V[key][hd]
#pragma unroll
    for (int kc = 0; kc < 4; ++kc) {
      int kb = kc * 32 + koff;
      bfrag pF[4], vF[4];
#pragma unroll
      for (int m = 0; m < 4; ++m) {
        int rp = wr * 64 + m * 16 + l15;
        pF[m] = *(const bfrag*)((char*)Ps + rp * 256 + ((kb * 2) ^ ((rp & 7) << 4)));
      }
#pragma unroll
      for (int n = 0; n < 4; ++n) {
        int rv = wc * 64 + n * 16 + l15;
        vF[n] = *(const bfrag*)((char*)KVs + rv * 256 + ((kb * 2) ^ ((rv & 7) << 4)));
      }
#pragma unroll
      for (int m = 0; m < 4; ++m)
#pragma unroll
        for (int n = 0; n < 4; ++n)
          outa[m][n] = __builtin_amdgcn_mfma_f32_16x16x32_bf16(pF[m], vF[n], outa[m][n], 0, 0, 0);
    }
    __syncthreads();  // V/Ps reads done before next-tile overwrite
  }
  // write fp32 partial [128][128]
  {
    float* Po = Pacc + (size_t)bx * 16384;
    const int cr = (lane >> 4) << 2;
#pragma unroll
    for (int m = 0; m < 4; ++m)
#pragma unroll
      for (int n = 0; n < 4; ++n) {
        int r2 = wr * 64 + m * 16 + cr;
        int c = wc * 64 + n * 16 + l15;
#pragma unroll
        for (int j = 0; j < 4; ++j) Po[(r2 + j) * 128 + c] = outa[m][n][j];
      }
  }
}

// ------------- reduce partials -> AO bf16 [s][h*128+d] -------------
__global__ __launch_bounds__(256) void qwen_reduce(const float* __restrict__ Pacc,
                                                   unsigned short* __restrict__ AO) {
  const int qt = blockIdx.x, h = blockIdx.y;
  int c0 = 0;
  for (int q = 0; q < qt; ++q) c0 += (q >> 2) + 1;
  const int nch = (qt >> 2) + 1;
  const float* base = Pacc + ((size_t)h * 40 + c0) * 16384;
  const int t = threadIdx.x;
#pragma unroll
  for (int i = 0; i < 16; ++i) {
    int idx = (i * 256 + t) * 4;
    f32x4 s = *(const f32x4*)(base + idx);
    for (int c = 1; c < nch; ++c) {
      f32x4 v = *(const f32x4*)(base + (size_t)c * 16384 + idx);
      s[0] += v[0]; s[1] += v[1]; s[2] += v[2]; s[3] += v[3];
    }
    int row = idx >> 7, col = idx & 127;
    short4v o;
    o[0] = (short)f2b(s[0]); o[1] = (short)f2b(s[1]);
    o[2] = (short)f2b(s[2]); o[3] = (short)f2b(s[3]);
    *(short4v*)(AO + (size_t)(qt * 128 + row) * kD + (h << 7) + col) = o;
  }
}

extern "C" void kernel_launch(void* const* d_in, const int* in_sizes, int n_in,
                              void* d_out, int out_size, void* d_ws, size_t ws_size,
                              hipStream_t stream) {
  (void)in_sizes; (void)n_in; (void)out_size; (void)ws_size;
  const float* hidden = (const float*)d_in[0];
  const float* cosb   = (const float*)d_in[1];
  const float* sinb   = (const float*)d_in[2];
  const float* qw     = (const float*)d_in[3];
  const float* kw     = (const float*)d_in[4];
  const float* vw     = (const float*)d_in[5];
  const float* ow     = (const float*)d_in[6];
  const float* qnw    = (const float*)d_in[7];
  const float* knw    = (const float*)d_in[8];
  const float* qden   = (const float*)d_in[9];
  const float* kden   = (const float*)d_in[10];
  const float* rd     = (const float*)d_in[11];
  float* out = (float*)d_out;

  char* ws = (char*)d_ws;
  // layout: [0,8) hsb | [8,24) Wt | [24,56) Cqkv | [56,64) Qb | [64,68) Kswz |
  //         [68,72) Vswz | [72,80) AO | [80,88) Ot ; Pacc overlays [0,40) (dead by attn)
  unsigned short* hsb  = (unsigned short*)(ws + 0 * MB);
  unsigned short* Wt   = (unsigned short*)(ws + 8 * MB);
  float*          Cqkv = (float*)(ws + 24 * MB);
  unsigned short* Qb   = (unsigned short*)(ws + 56 * MB);
  unsigned short* Kswz = (unsigned short*)(ws + 64 * MB);
  unsigned short* Vswz = (unsigned short*)(ws + 68 * MB);
  unsigned short* AO   = (unsigned short*)(ws + 72 * MB);
  unsigned short* Ot   = (unsigned short*)(ws + 80 * MB);
  float*          Pacc = (float*)(ws + 0 * MB);  // 640*64KB = 40MB

  qwen_cast_bf16<<<4096, 256, 0, stream>>>(hidden, hsb, 2048 * 2048 / 4);
  qwen_tw<<<dim3(32, 32), 256, 0, stream>>>(qw, 2048, 2048, Wt, 2048);
  qwen_tw<<<dim3(16, 32), 256, 0, stream>>>(kw, 2048, 1024, Wt + (size_t)2048 * 2048, 2048);
  qwen_tw<<<dim3(16, 32), 256, 0, stream>>>(vw, 2048, 1024, Wt + (size_t)3072 * 2048, 2048);
  qwen_tw<<<dim3(32, 32), 256, 0, stream>>>(ow, 2048, 2048, Ot, 2048);
  qwen_gemm_bt<<<dim3(16, 32), 256, 0, stream>>>(hsb, Wt, Cqkv, 2048, 4096, 2048);
  qwen_rope_qk<<<2048, 256, 0, stream>>>(Cqkv, cosb, sinb, qnw, knw, qden, kden, Qb, Kswz);
  qwen_vtr<<<dim3(8, 32, 2), 256, 0, stream>>>(Cqkv, Vswz);
  qwen_attn<<<640, 256, 0, stream>>>(Qb, Kswz, Vswz, rd, Pacc);
  qwen_reduce<<<dim3(16, 16), 256, 0, stream>>>(Pacc, AO);
  qwen_gemm_bt<<<dim3(16, 16), 256, 0, stream>>>(AO, Ot, out, 2048, 2048, 2048);
}

// Round 3
// 200.852 us; speedup vs baseline: 1.4669x; 1.4669x over previous
//
#include <hip/hip_runtime.h>
#include <cstdint>
#include <cstddef>

// Qwen3AttentionModified: B=1 S=2048 D=2048 H=16 KVH=8 HD=128
// cast hs->bf16; transpose+cast weights; QKV GEMM (+XCD swizzle); RoPE -> Q/K bf16;
// V -> bf16 [kvh][d][s]; attention: barrier-light, K/V direct-from-L2 (kvh->XCD bound),
// qt32-pair balanced, P via tiny LDS; O GEMM -> fp32 d_out.

namespace {
constexpr int kS = 2048;
constexpr int kD = 2048;
constexpr int kH = 16;
constexpr int kKVH = 8;
constexpr int kHD = 128;
constexpr float kScale = 0.08838834764831845f;  // 128^-0.5
constexpr size_t MB = 1u << 20;
}  // namespace

using f32x4 = __attribute__((ext_vector_type(4))) float;
using bfrag = __attribute__((ext_vector_type(8))) short;   // 8 x bf16 (4 VGPR)
using float4v = __attribute__((ext_vector_type(4))) float;
using short4v = __attribute__((ext_vector_type(4))) short;

__device__ __forceinline__ unsigned short f2b(float f) {
  union { float f; unsigned u; } x; x.f = f;
  unsigned r = x.u + 0x7FFFu + ((x.u >> 16) & 1u);  // RNE
  return (unsigned short)(r >> 16);
}

__device__ __forceinline__ void gload_lds16(const void* g, void* l) {
  __builtin_amdgcn_global_load_lds(
      (const __attribute__((address_space(1))) unsigned*)g,
      (__attribute__((address_space(3))) unsigned*)l, 16, 0, 0);
}

// ---------------- cast fp32 -> bf16 ----------------
__global__ __launch_bounds__(256) void qwen_cast_bf16(const float* __restrict__ in,
                                                      unsigned short* __restrict__ out,
                                                      int n4) {
  int i = blockIdx.x * 256 + threadIdx.x;
  if (i >= n4) return;
  float4v v = *(const float4v*)(in + (size_t)i * 4);
  short4v o;
  o[0] = (short)f2b(v[0]); o[1] = (short)f2b(v[1]);
  o[2] = (short)f2b(v[2]); o[3] = (short)f2b(v[3]);
  *(short4v*)(out + (size_t)i * 4) = o;
}

// ------------- transpose + cast: fp32 [R][C] -> bf16 [C][ldo] -------------
__global__ __launch_bounds__(256) void qwen_tw(const float* __restrict__ in, int R, int C,
                                               unsigned short* __restrict__ out, int ldo) {
  __shared__ float t[64][65];
  int c0 = blockIdx.x * 64, r0 = blockIdx.y * 64;
  int tr = threadIdx.x >> 6, tc = threadIdx.x & 63;
#pragma unroll
  for (int p = 0; p < 16; ++p) {
    int i = p * 4 + tr;
    t[i][tc] = in[(size_t)(r0 + i) * C + c0 + tc];
  }
  __syncthreads();
#pragma unroll
  for (int p = 0; p < 16; ++p) {
    int i = p * 4 + tr;
    out[(size_t)(c0 + i) * ldo + r0 + tc] = f2b(t[tc][i]);
  }
}

// ------------- GEMM (m97 structure + XCD swizzle): C fp32 = A bf16 @ Bt bf16 -------------
__global__ __launch_bounds__(256) void qwen_gemm_bt(const unsigned short* __restrict__ A,
                                                    const unsigned short* __restrict__ Bt,
                                                    float* __restrict__ C,
                                                    int M, int N, int K) {
  __shared__ unsigned short As[128 * 32];
  __shared__ unsigned short Bs[128 * 32];
  const int nwg = gridDim.x * gridDim.y;
  int lin = blockIdx.y * gridDim.x + blockIdx.x;
  if ((nwg & 7) == 0) { int qq = nwg >> 3; lin = (lin & 7) * qq + (lin >> 3); }
  const int bxx = lin % gridDim.x, byy = lin / gridDim.x;
  const int tid = threadIdx.x;
  const int lane = tid & 63;
  const int w = tid >> 6;
  const int wr = w >> 1, wc = w & 1;
  const int row0 = bxx * 128, col0 = byy * 128;
  f32x4 acc[4][4] = {};
  const int koff = (lane >> 4) << 3;
  const int rA = wr * 64 + (lane & 15);
  const int rB = wc * 64 + (lane & 15);
  for (int kt = 0; kt < K; kt += 32) {
#pragma unroll
    for (int c = 0; c < 2; ++c) {
      int off = w * 2048 + c * 1024;
      int e = (off >> 1) + lane * 8;
      int r = e >> 5, cc = e & 31;
      gload_lds16(A + (size_t)(row0 + r) * K + kt + cc, (char*)As + off);
      gload_lds16(Bt + (size_t)(col0 + r) * K + kt + cc, (char*)Bs + off);
    }
    __syncthreads();
    bfrag aF[4], bF[4];
#pragma unroll
    for (int m = 0; m < 4; ++m) aF[m] = *(const bfrag*)(As + (rA + m * 16) * 32 + koff);
#pragma unroll
    for (int n = 0; n < 4; ++n) bF[n] = *(const bfrag*)(Bs + (rB + n * 16) * 32 + koff);
#pragma unroll
    for (int m = 0; m < 4; ++m)
#pragma unroll
      for (int n = 0; n < 4; ++n)
        acc[m][n] = __builtin_amdgcn_mfma_f32_16x16x32_bf16(aF[m], bF[n], acc[m][n], 0, 0, 0);
    __syncthreads();
  }
  const int cr = (lane >> 4) << 2;
  const int cc2 = lane & 15;
#pragma unroll
  for (int m = 0; m < 4; ++m)
#pragma unroll
    for (int n = 0; n < 4; ++n) {
      int r = row0 + wr * 64 + m * 16 + cr;
      int c = col0 + wc * 64 + n * 16 + cc2;
#pragma unroll
      for (int j = 0; j < 4; ++j) C[(size_t)(r + j) * N + c] = acc[m][n][j];
    }
}

// ------------- RoPE epilogue: Q,K -> bf16 [h][s][d] (validated r1 version) -------------
__global__ __launch_bounds__(256) void qwen_rope_qk(const float* __restrict__ Cqkv,
                                                    const float* __restrict__ cosb,
                                                    const float* __restrict__ sinb,
                                                    const float* __restrict__ qnw,
                                                    const float* __restrict__ knw,
                                                    const float* __restrict__ qden,
                                                    const float* __restrict__ kden,
                                                    unsigned short* __restrict__ Qb,
                                                    unsigned short* __restrict__ Kb) {
  int s = blockIdx.x;
  int t = threadIdx.x;
  const float* row = Cqkv + (size_t)s * 4096;
  const float* cs = cosb + (size_t)s * kHD;
  const float* sn = sinb + (size_t)s * kHD;
#pragma unroll
  for (int rep = 0; rep < 8; ++rep) {
    int idx = rep * 256 + t;
    int h = idx >> 7, d = idx & 127;
    float dn = qden[s * kH + h];
    float v = row[idx] * dn * qnw[d];
    float pv = row[(h << 7) + (d ^ 64)] * dn * qnw[d ^ 64];
    float rot = (d < 64) ? -pv : pv;
    Qb[((size_t)h * kS + s) * kHD + d] = f2b(v * cs[d] + rot * sn[d]);
  }
#pragma unroll
  for (int rep = 0; rep < 4; ++rep) {
    int idx = rep * 256 + t;
    int h = idx >> 7, d = idx & 127;
    float dn = kden[s * kKVH + h];
    float v = row[2048 + idx] * dn * knw[d];
    float pv = row[2048 + (h << 7) + (d ^ 64)] * dn * knw[d ^ 64];
    float rot = (d < 64) ? -pv : pv;
    Kb[((size_t)h * kS + s) * kHD + d] = f2b(v * cs[d] + rot * sn[d]);
  }
}

// ------------- V -> bf16 [kvh][d][s] (validated r1 version) -------------
__global__ __launch_bounds__(256) void qwen_vtr(const float* __restrict__ Cqkv,
                                                unsigned short* __restrict__ Vt) {
  __shared__ float t[64][65];
  int kvh = blockIdx.x, st = blockIdx.y, dt = blockIdx.z;
  int s0 = st * 64, d0 = dt * 64;
  int tr = threadIdx.x >> 6, tc = threadIdx.x & 63;
#pragma unroll
  for (int p = 0; p < 16; ++p) {
    int i = p * 4 + tr;
    t[i][tc] = Cqkv[(size_t)(s0 + i) * 4096 + 3072 + (kvh << 7) + d0 + tc];
  }
  __syncthreads();
#pragma unroll
  for (int p = 0; p < 16; ++p) {
    int i = p * 4 + tr;
    Vt[(size_t)((kvh << 7) + d0 + i) * kS + s0 + tc] = f2b(t[tc][i]);
  }
}

// ------------- attention: barrier-light, K/V from L2, qt32-pair balanced -------------
// block (512 total): kvh = bid&7 (XCD-bound); h = kvh*2 + (rr&1); pair pj = rr>>1.
// phases qt = pj and 63-pj (32 q-rows each); chunks of 64 keys, nch = qt/2+1 (total 33).
// QK: wave w computes key-quarter [w*16,w*16+16); PV: wave w computes d-quarter [w*32,..).
#define CHUNK_BODY(KC, KN)                                                              \
  do {                                                                                  \
    f32x4 sc[2] = {{0, 0, 0, 0}, {0, 0, 0, 0}};                                         \
    _Pragma("unroll") for (int m = 0; m < 2; ++m)                                       \
        _Pragma("unroll") for (int kc = 0; kc < 4; ++kc)                                \
            sc[m] = __builtin_amdgcn_mfma_f32_16x16x32_bf16(qF[m][kc], KC[kc], sc[m],   \
                                                            0, 0, 0);                   \
    const int keyg = c * 64 + w16l;                                                     \
    _Pragma("unroll") for (int m = 0; m < 2; ++m)                                       \
        _Pragma("unroll") for (int j = 0; j < 4; ++j) {                                 \
      int qg = q0 + m * 16 + g * 4 + j;                                                 \
      float tt = sc[m][j] * kScale + ((keyg <= qg) ? 7.0f : 0.0f);                      \
      float y = tt * inv[m][j];                                                         \
      float y2 = y * y, y4 = y2 * y2;                                                   \
      Pl[m * 16 + g * 4 + j][w16l] = f2b(y4 * y4);                                      \
    }                                                                                   \
    if (c + 1 < nch) {                                                                  \
      const unsigned short* kp = Kbase + (size_t)(c + 1) * 8192;                        \
      _Pragma("unroll") for (int kc = 0; kc < 4; ++kc)                                  \
          KN[kc] = *(const bfrag*)(kp + kc * 32);                                       \
    }                                                                                   \
    bfrag vF[2][2];                                                                     \
    {                                                                                   \
      const unsigned short* vp = Vbase + c * 64;                                        \
      _Pragma("unroll") for (int n2 = 0; n2 < 2; ++n2)                                  \
          _Pragma("unroll") for (int k2 = 0; k2 < 2; ++k2)                              \
              vF[n2][k2] = *(const bfrag*)(vp + (size_t)n2 * 16 * kS + k2 * 32);        \
    }                                                                                   \
    __syncthreads();                                                                    \
    bfrag pF[2][2];                                                                     \
    _Pragma("unroll") for (int m = 0; m < 2; ++m)                                       \
        _Pragma("unroll") for (int k2 = 0; k2 < 2; ++k2)                                \
            pF[m][k2] = *(const bfrag*)(&Pl[m * 16 + l15][k2 * 32 + g * 8]);            \
    _Pragma("unroll") for (int m = 0; m < 2; ++m)                                       \
        _Pragma("unroll") for (int n2 = 0; n2 < 2; ++n2)                                \
            _Pragma("unroll") for (int k2 = 0; k2 < 2; ++k2)                            \
                outa[m][n2] = __builtin_amdgcn_mfma_f32_16x16x32_bf16(                  \
                    pF[m][k2], vF[n2][k2], outa[m][n2], 0, 0, 0);                       \
    __syncthreads();                                                                    \
  } while (0)

__global__ __launch_bounds__(256, 2) void qwen_attn(const unsigned short* __restrict__ Qb,
                                                    const unsigned short* __restrict__ Kb,
                                                    const unsigned short* __restrict__ Vtb,
                                                    const float* __restrict__ rd,
                                                    unsigned short* __restrict__ AO) {
  __shared__ unsigned short Pl[32][72];  // P tile, padded stride (2-way max on b128 reads)
  const int bid = blockIdx.x;
  const int kvh = bid & 7;               // XCD binding: per-XCD KV set = 1MB (L2-resident)
  const int rr = bid >> 3;
  const int h = kvh * 2 + (rr & 1);
  const int pj = rr >> 1;                // 0..31
  const int tid = threadIdx.x, lane = tid & 63, w = tid >> 6;
  const int l15 = lane & 15, g = lane >> 4;
  const int w16l = w * 16 + l15;
  const unsigned short* Kbase = Kb + ((size_t)kvh * kS + w16l) * kHD + g * 8;
  const unsigned short* Vbase = Vtb + ((size_t)(kvh * kHD) + w * 32 + l15) * kS + g * 8;
  const float* rdh = rd + (size_t)h * kS;

#pragma unroll 1
  for (int phase = 0; phase < 2; ++phase) {
    const int qt = phase ? (63 - pj) : pj;
    const int q0 = qt * 32;
    const int nch = (qt >> 1) + 1;
    bfrag qF[2][4];
#pragma unroll
    for (int m = 0; m < 2; ++m)
#pragma unroll
      for (int kc = 0; kc < 4; ++kc)
        qF[m][kc] = *(const bfrag*)(Qb + ((size_t)h * kS + q0 + m * 16 + l15) * kHD +
                                    kc * 32 + g * 8);
    float inv[2][4];
#pragma unroll
    for (int m = 0; m < 2; ++m)
#pragma unroll
      for (int j = 0; j < 4; ++j) inv[m][j] = 1.0f / rdh[q0 + m * 16 + g * 4 + j];
    f32x4 outa[2][2] = {};
    bfrag kA[4], kB[4];
#pragma unroll
    for (int kc = 0; kc < 4; ++kc) kA[kc] = *(const bfrag*)(Kbase + kc * 32);
    int c = 0;
    while (true) {
      CHUNK_BODY(kA, kB);
      ++c; if (c == nch) break;
      CHUNK_BODY(kB, kA);
      ++c; if (c == nch) break;
    }
    // AO bf16 [s][h*128+d]
    unsigned short* ao = AO + (size_t)q0 * kD + h * 128 + w * 32 + l15;
#pragma unroll
    for (int m = 0; m < 2; ++m)
#pragma unroll
      for (int n2 = 0; n2 < 2; ++n2)
#pragma unroll
        for (int j = 0; j < 4; ++j)
          ao[(size_t)(m * 16 + g * 4 + j) * kD + n2 * 16] = f2b(outa[m][n2][j]);
  }
}

extern "C" void kernel_launch(void* const* d_in, const int* in_sizes, int n_in,
                              void* d_out, int out_size, void* d_ws, size_t ws_size,
                              hipStream_t stream) {
  (void)in_sizes; (void)n_in; (void)out_size; (void)ws_size;
  const float* hidden = (const float*)d_in[0];
  const float* cosb   = (const float*)d_in[1];
  const float* sinb   = (const float*)d_in[2];
  const float* qw     = (const float*)d_in[3];
  const float* kw     = (const float*)d_in[4];
  const float* vw     = (const float*)d_in[5];
  const float* ow     = (const float*)d_in[6];
  const float* qnw    = (const float*)d_in[7];
  const float* knw    = (const float*)d_in[8];
  const float* qden   = (const float*)d_in[9];
  const float* kden   = (const float*)d_in[10];
  const float* rd     = (const float*)d_in[11];
  float* out = (float*)d_out;

  char* ws = (char*)d_ws;
  unsigned short* hsb  = (unsigned short*)(ws + 0 * MB);   //  8 MB
  unsigned short* Wt   = (unsigned short*)(ws + 8 * MB);   // 16 MB
  float*          Cqkv = (float*)(ws + 24 * MB);           // 32 MB
  unsigned short* Qb   = (unsigned short*)(ws + 56 * MB);  //  8 MB
  unsigned short* Kb   = (unsigned short*)(ws + 64 * MB);  //  4 MB
  unsigned short* Vtb  = (unsigned short*)(ws + 68 * MB);  //  4 MB
  unsigned short* AO   = (unsigned short*)(ws + 72 * MB);  //  8 MB
  unsigned short* Ot   = (unsigned short*)(ws + 80 * MB);  //  8 MB

  qwen_cast_bf16<<<4096, 256, 0, stream>>>(hidden, hsb, 2048 * 2048 / 4);
  qwen_tw<<<dim3(32, 32), 256, 0, stream>>>(qw, 2048, 2048, Wt, 2048);
  qwen_tw<<<dim3(16, 32), 256, 0, stream>>>(kw, 2048, 1024, Wt + (size_t)2048 * 2048, 2048);
  qwen_tw<<<dim3(16, 32), 256, 0, stream>>>(vw, 2048, 1024, Wt + (size_t)3072 * 2048, 2048);
  qwen_tw<<<dim3(32, 32), 256, 0, stream>>>(ow, 2048, 2048, Ot, 2048);
  qwen_gemm_bt<<<dim3(16, 32), 256, 0, stream>>>(hsb, Wt, Cqkv, 2048, 4096, 2048);
  qwen_rope_qk<<<2048, 256, 0, stream>>>(Cqkv, cosb, sinb, qnw, knw, qden, kden, Qb, Kb);
  qwen_vtr<<<dim3(8, 32, 2), 256, 0, stream>>>(Cqkv, Vtb);
  qwen_attn<<<512, 256, 0, stream>>>(Qb, Kb, Vtb, rd, AO);
  qwen_gemm_bt<<<dim3(16, 16), 256, 0, stream>>>(AO, Ot, out, 2048, 2048, 2048);
}